// Round 1
// baseline (16.475 us; speedup 1.0000x reference)
//
#include <hip/hip_runtime.h>
#include <hip/hip_bf16.h>

// Quantum circuit collapses to closed form:
//   Pre-CNOT state is a product state (all gates single-qubit, |0..0> init).
//   Per-wire <Z> before CNOTs: z_k = cos(pi*x_k) * (cos(w_k) - sin(pi*x_k)*sin(w_k))
//   CNOT ring => new_bit_j = XOR_{k<=j} b_k (j>=1), new_bit_0 = XOR_{k>=1} b_k
//   1-2*XOR(bits) factorizes over independent bits =>
//     out[b,j] = prod_{k=0..j} z_k   (j >= 1)
//     out[b,0] = prod_{k=1..13} z_k

#define NQ 14

__global__ void qlayer_closed_form(const float* __restrict__ x,
                                   const float* __restrict__ w,
                                   float* __restrict__ out,
                                   int B) {
    int b = blockIdx.x * blockDim.x + threadIdx.x;
    if (b >= B) return;

    const float PI = 3.14159265358979323846f;

    float z[NQ];
#pragma unroll
    for (int k = 0; k < NQ; ++k) {
        float a = PI * x[b * NQ + k];
        float wk = w[k];
        float sa, ca, sw, cw;
        sincosf(a, &sa, &ca);
        sincosf(wk, &sw, &cw);
        z[k] = ca * (cw - sa * sw);
    }

    float p = z[0];      // running prefix product incl. z0
    float ptail = 1.0f;  // product of z1..z13
#pragma unroll
    for (int j = 1; j < NQ; ++j) {
        p *= z[j];
        ptail *= z[j];
        out[b * NQ + j] = p;
    }
    out[b * NQ + 0] = ptail;
}

extern "C" void kernel_launch(void* const* d_in, const int* in_sizes, int n_in,
                              void* d_out, int out_size, void* d_ws, size_t ws_size,
                              hipStream_t stream) {
    const float* x = (const float*)d_in[0];   // [B, 14]
    const float* w = (const float*)d_in[1];   // [1, 14]
    float* out = (float*)d_out;               // [B, 14]

    int B = in_sizes[0] / NQ;

    int block = 64;
    int grid = (B + block - 1) / block;
    qlayer_closed_form<<<grid, block, 0, stream>>>(x, w, out, B);
}